// Round 26
// baseline (36.475 us; speedup 1.0000x reference)
//
#include <hip/hip_runtime.h>
#include <math.h>

#define NPRED 16384
#define NGT   32768
#define BETA  0.45f
#define GAMMA 0.45f

#define NGROUP 32                 // split groups == stored keys per pred
#define SPG    4                  // splits per nn block (looped)
#define GSPLIT (NGROUP * SPG)     // 128 splits x 256 rows
#define NTILE  (NGT / 32)         // 1024 tiles of 32 gt rows (10-bit id)
#define TPS    8                  // tiles per split -> 8 KB per LDS buffer
#define PB     256                // preds per nn block (4 waves x 64)
#define NN_BX  (NPRED / PB)       // 64 chunks
#define RESB   (NPRED / 8)        // 2048 rescan blocks (8 preds each)

typedef float f32x16 __attribute__((ext_vector_type(16)));
typedef short short8 __attribute__((ext_vector_type(8)));

__device__ __forceinline__ unsigned bf16h(float f) {          // RNE f32->bf16
    unsigned u = __float_as_uint(f);
    return (u + 0x7FFFu + ((u >> 16) & 1u)) >> 16;
}
__device__ __forceinline__ float bf16f(unsigned h) { return __uint_as_float(h << 16); }
__device__ __forceinline__ unsigned pk2(unsigned lo, unsigned hi) { return lo | (hi << 16); }

// R26: MFMA with INLINE-0 C operand (kills the 16-reg zacc bank) and "=&v"
// destination (arch VGPRs, R23's win).
#define MFMA0(D, A, B)                                                         \
    asm("v_mfma_f32_32x32x16_bf16 %0, %1, %2, 0"                               \
        : "=&v"(D) : "v"(A), "v"(B))

// R24 (kept): explicit v_min3 tree, 9 ops per 16-acc tile.
__device__ __forceinline__ float tile_key3(const f32x16 acc, float vmask, int gtile) {
    float m0, m1, m2, m3, m4, n0, n1, key;
    asm("v_min3_f32 %0, %1, %2, %3" : "=v"(m0) : "v"(acc[0]),  "v"(acc[1]),  "v"(acc[2]));
    asm("v_min3_f32 %0, %1, %2, %3" : "=v"(m1) : "v"(acc[3]),  "v"(acc[4]),  "v"(acc[5]));
    asm("v_min3_f32 %0, %1, %2, %3" : "=v"(m2) : "v"(acc[6]),  "v"(acc[7]),  "v"(acc[8]));
    asm("v_min3_f32 %0, %1, %2, %3" : "=v"(m3) : "v"(acc[9]),  "v"(acc[10]), "v"(acc[11]));
    asm("v_min3_f32 %0, %1, %2, %3" : "=v"(m4) : "v"(acc[12]), "v"(acc[13]), "v"(acc[14]));
    asm("v_min3_f32 %0, %1, %2, %3" : "=v"(n0) : "v"(m0), "v"(m1), "v"(m2));
    asm("v_min3_f32 %0, %1, %2, %3" : "=v"(n1) : "v"(m3), "v"(m4), "v"(acc[15]));
    asm("v_min_f32 %0, %1, %2"      : "=v"(key) : "v"(n0), "v"(n1));
    asm("v_and_or_b32 %0, %1, %2, %3" : "+v"(key) : "v"(vmask), "s"(gtile));
    return key;
}

__device__ __forceinline__ void gload_lds16(const uint4* g, uint4* l) {
    __builtin_amdgcn_global_load_lds(
        (const __attribute__((address_space(1))) void*)g,
        (__attribute__((address_space(3))) void*)l, 16, 0, 0);
}

// ---------------------------------------------------------------------------
// prep: convert gt rows to split-bf16 A-fragments ONCE, tile-major so each
// 256-row split is an 8 KB LINEAR block (global_load_lds-compatible: wave-
// uniform LDS base + lane x 16 [m104]). Layout verified exact (absmax 0.0,
// R10-R25):  A row j: k0..7=[xh,xh,xl,xl,yh,yh,yl,yl]
//                     k8..15=[zh,zh,zl,zl,g2h,g2l,0,0]
// ---------------------------------------------------------------------------
__global__ __launch_bounds__(256) void prep_kernel(
    const float* __restrict__ gt, uint4* __restrict__ AFg)
{
    const int j = blockIdx.x * 256 + threadIdx.x;
    const float x = gt[j * 6 + 0], y = gt[j * 6 + 1], z = gt[j * 6 + 2];
    const float g2 = fmaf(x, x, fmaf(y, y, z * z));
    const unsigned xh = bf16h(x),  yh = bf16h(y),  zh = bf16h(z),  gh = bf16h(g2);
    const unsigned xl = bf16h(x - bf16f(xh)), yl = bf16h(y - bf16f(yh));
    const unsigned zl = bf16h(z - bf16f(zh)), gl = bf16h(g2 - bf16f(gh));
    const int tile = j >> 5, r = j & 31;
    AFg[tile * 64 + r]      = make_uint4(pk2(xh, xh), pk2(xl, xl), pk2(yh, yh), pk2(yl, yl));
    AFg[tile * 64 + 32 + r] = make_uint4(pk2(zh, zh), pk2(zl, zl), pk2(gh, gl), 0u);
}

// ---------------------------------------------------------------------------
// nn (R26): 2048 blocks = 64 chunks x 32 groups, 4 splits x 256 rows each.
// Staging = pure async global_load_lds from AFg (no conversion VALU, no
// staging registers); double-buffered 2x8 KB; one vmcnt(0)+barrier per split.
// Occupancy target: 8 blocks/CU = 32 waves/CU (needs <=64 VGPR, forced by
// __launch_bounds__(256,8); interleaved trees keep 2 accs live, inline-0 C).
// Math verified exact (absmax 0.0, R10-R25); C col=lane&31 [m74/m101].
// Keys: (bits(tile_min) & 0xFFFFFC00) | tile10, min3 fold.
// NO atomics/fences (R15).
// ---------------------------------------------------------------------------
__global__ __launch_bounds__(256, 8) void nn_kernel(
    const float* __restrict__ pred,
    const uint4* __restrict__ AFg,
    unsigned* __restrict__ packed2)
{
    __shared__ uint4 AF[2][TPS * 64];                   // 2 x 8 KB

    const int l  = threadIdx.x & 63;
    const int w  = threadIdx.x >> 6;

    // ---- two B fragments (pred groups c and c+32), built once per block
    const int pbase = blockIdx.x * PB + w * 64;
    const int c     = l & 31;
    const bool hi   = l >= 32;
    uint4 bu0, bu1;
    {
        const int pi = pbase + c;
        const float x = pred[pi * 6 + 0], y = pred[pi * 6 + 1], zc = pred[pi * 6 + 2];
        const float mx = -2.0f * x, my = -2.0f * y, mz = -2.0f * zc;
        const unsigned xh = bf16h(mx), yh = bf16h(my), zh = bf16h(mz);
        const unsigned xl = bf16h(mx - bf16f(xh)), yl = bf16h(my - bf16f(yh));
        const unsigned zl = bf16h(mz - bf16f(zh));
        bu0.x = hi ? pk2(zh, zl) : pk2(xh, xl);
        bu0.y = bu0.x;
        bu0.z = hi ? 0x3F803F80u : pk2(yh, yl);
        bu0.w = hi ? 0u : bu0.z;
    }
    {
        const int pi = pbase + 32 + c;
        const float x = pred[pi * 6 + 0], y = pred[pi * 6 + 1], zc = pred[pi * 6 + 2];
        const float mx = -2.0f * x, my = -2.0f * y, mz = -2.0f * zc;
        const unsigned xh = bf16h(mx), yh = bf16h(my), zh = bf16h(mz);
        const unsigned xl = bf16h(mx - bf16f(xh)), yl = bf16h(my - bf16f(yh));
        const unsigned zl = bf16h(mz - bf16f(zh));
        bu1.x = hi ? pk2(zh, zl) : pk2(xh, xl);
        bu1.y = bu1.x;
        bu1.z = hi ? 0x3F803F80u : pk2(yh, yl);
        bu1.w = hi ? 0u : bu1.z;
    }
    const short8 bv0 = *(const short8*)&bu0;
    const short8 bv1 = *(const short8*)&bu1;
    const float vmask = __uint_as_float(0xFFFFFC00u);

    float kmin0 = 1e30f, kmin1 = 1e30f;
    const int sp0 = blockIdx.y * SPG;

    // wave w stages 2 KB (128 uint4) per split: 2 x global_load_lds(16B)
#define STAGE(BUF, SP)                                                         \
    {                                                                          \
        const uint4* src = AFg + (size_t)(SP) * (TPS * 64) + w * 128 + l;      \
        gload_lds16(src,      &BUF[w * 128]);                                  \
        gload_lds16(src + 64, &BUF[w * 128 + 64]);                             \
    }

    STAGE(AF[0], sp0)
    asm volatile("s_waitcnt vmcnt(0)" ::: "memory");
    __syncthreads();

#pragma unroll 1
    for (int u = 0; u < SPG; ++u) {
        const int sp = sp0 + u;
        uint4* cur = AF[u & 1];
        uint4* nxt = AF[(u + 1) & 1];

        if (u + 1 < SPG) STAGE(nxt, sp + 1)   // async, lands during compute

        const int t0 = sp * TPS;
#pragma unroll 1
        for (int tt = 0; tt < TPS; tt += 2) {
            const uint4 aua = cur[tt * 64 + l];
            const uint4 aub = cur[(tt + 1) * 64 + l];
            const short8 ava = *(const short8*)&aua;
            const short8 avb = *(const short8*)&aub;
            const int ga = t0 + tt, gb = t0 + tt + 1;   // wave-uniform (SGPR)

            // interleaved: each tree consumes its acc before the next MFMA
            // needs a destination -> peak acc liveness = 2 (32 VGPRs)
            f32x16 a0, b0, a1, b1;
            MFMA0(a0, ava, bv0);
            MFMA0(b0, avb, bv0);
            const float ka0 = tile_key3(a0, vmask, ga);
            MFMA0(a1, ava, bv1);
            const float kb0 = tile_key3(b0, vmask, gb);
            MFMA0(b1, avb, bv1);
            asm("v_min3_f32 %0, %0, %1, %2" : "+v"(kmin0) : "v"(ka0), "v"(kb0));
            const float ka1 = tile_key3(a1, vmask, ga);
            const float kb1 = tile_key3(b1, vmask, gb);
            asm("v_min3_f32 %0, %0, %1, %2" : "+v"(kmin1) : "v"(ka1), "v"(kb1));
        }

        asm volatile("s_waitcnt vmcnt(0)" ::: "memory");   // nxt loads landed
        __syncthreads();
    }
#undef STAGE

    // cross-half merges (lane l <-> l+32 hold complementary rows)
    kmin0 = fminf(kmin0, __shfl_xor(kmin0, 32, 64));
    kmin1 = fminf(kmin1, __shfl_xor(kmin1, 32, 64));

    const float km = hi ? kmin1 : kmin0;
    packed2[(size_t)(pbase + l) * NGROUP + blockIdx.y] = __float_as_uint(km);
}

// ---------------------------------------------------------------------------
// rescan: 2048 blocks x 8 preds. Per pred: 32 lanes load the pred's 32 group
// keys (128 B contiguous), fminf shuffle-reduce, tile = bits & 0x3FF; exact
// fp32 argmin in the winning 32-row tile (first occurrence; float2 position
// loads); normals cosine; per-block partial. No atomics, no fences.
// ---------------------------------------------------------------------------
__global__ __launch_bounds__(256) void rescan_kernel(
    const float* __restrict__ pred,
    const float* __restrict__ gt,
    const unsigned* __restrict__ packed2,
    float* __restrict__ partials)
{
    __shared__ float part[8];
    const int w = threadIdx.x >> 6, l = threadIdx.x & 63;
    const int half = l >> 5, jl = l & 31;
    const int pi = blockIdx.x * 8 + w * 2 + half;

    const unsigned* kp = packed2 + (size_t)pi * NGROUP;
    float e = __uint_as_float(kp[jl]);
#pragma unroll
    for (int off = 16; off; off >>= 1)
        e = fminf(e, __shfl_xor(e, off, 32));
    const unsigned tix = __float_as_uint(e) & 0x3FFu;   // winning 32-row tile

    const int row = (int)tix * 32 + jl;
    const float2* gr = (const float2*)(gt + row * 6);   // 24 B rows, 8 B aligned
    const float2 ga = gr[0], gb = gr[1];
    const float gx = ga.x, gy = ga.y, gz = gb.x;
    const float g2 = fmaf(gx, gx, fmaf(gy, gy, gz * gz));
    const float2* pr = (const float2*)(pred + pi * 6);
    const float2 pa = pr[0], pb = pr[1];
    const float px = pa.x, py = pa.y, pz = pb.x;
    float d = fmaf(px, -2.0f * gx, fmaf(py, -2.0f * gy, fmaf(pz, -2.0f * gz, g2)));
    int jj = jl;
#pragma unroll
    for (int off = 16; off; off >>= 1) {
        const float d2 = __shfl_xor(d, off, 32);
        const int   j2 = __shfl_xor(jj, off, 32);
        const bool t = (d2 < d) || (d2 == d && j2 < jj);
        d  = t ? d2 : d;
        jj = t ? j2 : jj;
    }
    if (jl == 0) {
        const int idx = (int)tix * 32 + jj;
        const float nx = pred[pi * 6 + 3], ny = pred[pi * 6 + 4], nz = pred[pi * 6 + 5];
        const float ax = gt[idx * 6 + 3],  ay = gt[idx * 6 + 4],  az = gt[idx * 6 + 5];
        const float pn = fmaxf(sqrtf(fmaf(nx, nx, fmaf(ny, ny, nz * nz))), 1e-12f);
        const float gn = fmaxf(sqrtf(fmaf(ax, ax, fmaf(ay, ay, az * az))), 1e-12f);
        part[w * 2 + half] = 1.0f - fmaf(nx, ax, fmaf(ny, ay, nz * az)) / (pn * gn);
    }
    __syncthreads();
    if (threadIdx.x == 0) {
        float s = 0.f;
#pragma unroll
        for (int i = 0; i < 8; ++i) s += part[i];
        partials[blockIdx.x] = s;
    }
}

// ---------------------------------------------------------------------------
// final: sum partials + regularizer, single write to out[0].
// ---------------------------------------------------------------------------
__global__ __launch_bounds__(256) void final_kernel(
    const float* __restrict__ partials,
    const float* __restrict__ Rm,
    const float* __restrict__ tv,
    const float* __restrict__ sv,
    float* __restrict__ out)
{
    __shared__ float ws_[4];
    float s = 0.f;
    for (int i = threadIdx.x; i < RESB; i += 256) s += partials[i];
#pragma unroll
    for (int off = 32; off; off >>= 1) s += __shfl_down(s, off, 64);
    if ((threadIdx.x & 63) == 0) ws_[threadIdx.x >> 6] = s;
    __syncthreads();
    if (threadIdx.x == 0) {
        const float t = ws_[0] + ws_[1] + ws_[2] + ws_[3];
        float rs = 0.f;
#pragma unroll
        for (int k = 0; k < 9; ++k) {
            const float v = Rm[k] - ((k % 4 == 0) ? 1.0f : 0.0f);
            rs = fmaf(v, v, rs);
        }
        const float rot = sqrtf(rs);
        const float tr  = sqrtf(fmaf(tv[0], tv[0], fmaf(tv[1], tv[1], tv[2] * tv[2])));
        const float sc  = (sv[0] - 1.0f) * (sv[0] - 1.0f);
        out[0] = GAMMA * t / (float)NPRED + BETA * (rot + tr + sc);
    }
}

extern "C" void kernel_launch(void* const* d_in, const int* in_sizes, int n_in,
                              void* d_out, int out_size, void* d_ws, size_t ws_size,
                              hipStream_t stream)
{
    const float* pred = (const float*)d_in[0];
    const float* gt   = (const float*)d_in[1];
    const float* Rm   = (const float*)d_in[2];
    const float* tv   = (const float*)d_in[3];
    const float* sv   = (const float*)d_in[4];
    float* out = (float*)d_out;

    unsigned* packed2 = (unsigned*)d_ws;                                  // 2 MB
    float* partials   = (float*)((char*)d_ws + (size_t)NPRED * NGROUP * 4);   // 8 KB
    uint4* AFg = (uint4*)((char*)d_ws + (size_t)NPRED * NGROUP * 4 + 16384);  // 1 MB

    prep_kernel<<<NGT / 256, 256, 0, stream>>>(gt, AFg);
    nn_kernel<<<dim3(NN_BX, NGROUP), 256, 0, stream>>>(pred, AFg, packed2);
    rescan_kernel<<<RESB, 256, 0, stream>>>(pred, gt, packed2, partials);
    final_kernel<<<1, 256, 0, stream>>>(partials, Rm, tv, sv, out);
}

// Round 27
// 31.142 us; speedup vs baseline: 1.1712x; 1.1712x over previous
//
#include <hip/hip_runtime.h>
#include <math.h>

#define NPRED 16384
#define NGT   32768
#define BETA  0.45f
#define GAMMA 0.45f

#define NGROUP 16                 // split groups == stored keys per pred
#define SPG    4                  // splits per nn block (looped)
#define GSPLIT (NGROUP * SPG)     // 64 total splits
#define NTILE  (NGT / 32)         // 1024 tiles of 32 gt rows
#define TPS    (NTILE / GSPLIT)   // 16 tiles per split -> 16 KB per LDS buffer
#define PB     256                // preds per nn block (4 waves x 64)
#define NN_BX  (NPRED / PB)       // 64 chunks
#define RESB   (NPRED / 8)        // 2048 rescan blocks (8 preds each)

typedef float f32x16 __attribute__((ext_vector_type(16)));
typedef short short8 __attribute__((ext_vector_type(8)));

__device__ __forceinline__ unsigned bf16h(float f) {          // RNE f32->bf16
    unsigned u = __float_as_uint(f);
    return (u + 0x7FFFu + ((u >> 16) & 1u)) >> 16;
}
__device__ __forceinline__ float bf16f(unsigned h) { return __uint_as_float(h << 16); }
__device__ __forceinline__ unsigned pk2(unsigned lo, unsigned hi) { return lo | (hi << 16); }

// R23 (kept): "=&v" destination pins the 16-reg accumulator in ARCH VGPRs;
// hoisted zero C-bank avoids per-MFMA re-init.
#define MFMA_V(D, A, B, ZC)                                                    \
    asm("v_mfma_f32_32x32x16_bf16 %0, %1, %2, %3"                              \
        : "=&v"(D) : "v"(A), "v"(B), "v"(ZC))

// R24 (kept): explicit v_min3 tree, 9 ops per 16-acc tile.
__device__ __forceinline__ float tile_key3(const f32x16 acc, float vmask, int gtile) {
    float m0, m1, m2, m3, m4, n0, n1, key;
    asm("v_min3_f32 %0, %1, %2, %3" : "=v"(m0) : "v"(acc[0]),  "v"(acc[1]),  "v"(acc[2]));
    asm("v_min3_f32 %0, %1, %2, %3" : "=v"(m1) : "v"(acc[3]),  "v"(acc[4]),  "v"(acc[5]));
    asm("v_min3_f32 %0, %1, %2, %3" : "=v"(m2) : "v"(acc[6]),  "v"(acc[7]),  "v"(acc[8]));
    asm("v_min3_f32 %0, %1, %2, %3" : "=v"(m3) : "v"(acc[9]),  "v"(acc[10]), "v"(acc[11]));
    asm("v_min3_f32 %0, %1, %2, %3" : "=v"(m4) : "v"(acc[12]), "v"(acc[13]), "v"(acc[14]));
    asm("v_min3_f32 %0, %1, %2, %3" : "=v"(n0) : "v"(m0), "v"(m1), "v"(m2));
    asm("v_min3_f32 %0, %1, %2, %3" : "=v"(n1) : "v"(m3), "v"(m4), "v"(acc[15]));
    asm("v_min_f32 %0, %1, %2"      : "=v"(key) : "v"(n0), "v"(n1));
    asm("v_and_or_b32 %0, %1, %2, %3" : "+v"(key) : "v"(vmask), "s"(gtile));
    return key;
}

// convert one gt row (x,y,z) to its two A-fragment uint4s
__device__ __forceinline__ void conv_row(float x, float y, float z,
                                         uint4* __restrict__ buf, int lrow) {
    const float g2 = fmaf(x, x, fmaf(y, y, z * z));
    const unsigned xh = bf16h(x),  yh = bf16h(y),  zh = bf16h(z),  gh = bf16h(g2);
    const unsigned xl = bf16h(x - bf16f(xh)), yl = bf16h(y - bf16f(yh));
    const unsigned zl = bf16h(z - bf16f(zh)), gl = bf16h(g2 - bf16f(gh));
    const int tl = lrow >> 5, r = lrow & 31;
    buf[tl * 64 + r]      = make_uint4(pk2(xh, xh), pk2(xl, xl), pk2(yh, yh), pk2(yl, yl));
    buf[tl * 64 + 32 + r] = make_uint4(pk2(zh, zh), pk2(zl, zl), pk2(gh, gl), 0u);
}

// ---------------------------------------------------------------------------
// nn: R24 structure EXACTLY (best measured: 31.4 us total) + R27's single
// addition: s_setprio(1) around the compute region (T5) — the 4 independent
// blocks/CU give wave role-diversity (staging vs MFMA), so priority can keep
// the matrix pipe fed. Double-buffered, T14 async-STAGE split staging.
// Math verified exact (absmax 0.0, R10-R26):
//   A row j:  k0..7 = [xh,xh,xl,xl, yh,yh,yl,yl]  k8..15 = [zh,zh,zl,zl, g2h,g2l,0,0]
//   B col i:  k0..7 = [mxh,mxl,mxh,mxl, myh,myl,myh,myl]  k8..15 = [mzh,mzl,mzh,mzl,1,1,0,0]
// => acc[j][i] = g_j^2 - 2 p_i . g_j,  C col = lane&31 [m74/m101].
// Keys: (bits(tile_min) & 0xFFFFFC00) | tile10, min3 fold.
// NO atomics/fences (R15). Accs in VGPRs via asm MFMA (R23).
// ---------------------------------------------------------------------------
__global__ __launch_bounds__(256) void nn_kernel(
    const float* __restrict__ pred,
    const float* __restrict__ gt,
    unsigned* __restrict__ packed2)
{
    __shared__ uint4 AF[2][TPS * 64];                   // 2 x 16 KB

    const int l  = threadIdx.x & 63;
    const int w  = threadIdx.x >> 6;

    // ---- two B fragments (pred groups c and c+32), built once per block
    const int pbase = blockIdx.x * PB + w * 64;
    const int c     = l & 31;
    const bool hi   = l >= 32;
    uint4 bu0, bu1;
    {
        const int pi = pbase + c;
        const float x = pred[pi * 6 + 0], y = pred[pi * 6 + 1], zc = pred[pi * 6 + 2];
        const float mx = -2.0f * x, my = -2.0f * y, mz = -2.0f * zc;
        const unsigned xh = bf16h(mx), yh = bf16h(my), zh = bf16h(mz);
        const unsigned xl = bf16h(mx - bf16f(xh)), yl = bf16h(my - bf16f(yh));
        const unsigned zl = bf16h(mz - bf16f(zh));
        bu0.x = hi ? pk2(zh, zl) : pk2(xh, xl);
        bu0.y = bu0.x;
        bu0.z = hi ? 0x3F803F80u : pk2(yh, yl);
        bu0.w = hi ? 0u : bu0.z;
    }
    {
        const int pi = pbase + 32 + c;
        const float x = pred[pi * 6 + 0], y = pred[pi * 6 + 1], zc = pred[pi * 6 + 2];
        const float mx = -2.0f * x, my = -2.0f * y, mz = -2.0f * zc;
        const unsigned xh = bf16h(mx), yh = bf16h(my), zh = bf16h(mz);
        const unsigned xl = bf16h(mx - bf16f(xh)), yl = bf16h(my - bf16f(yh));
        const unsigned zl = bf16h(mz - bf16f(zh));
        bu1.x = hi ? pk2(zh, zl) : pk2(xh, xl);
        bu1.y = bu1.x;
        bu1.z = hi ? 0x3F803F80u : pk2(yh, yl);
        bu1.w = hi ? 0u : bu1.z;
    }
    const short8 bv0 = *(const short8*)&bu0;
    const short8 bv1 = *(const short8*)&bu1;
    const f32x16 zacc = {0.f,0.f,0.f,0.f,0.f,0.f,0.f,0.f,
                         0.f,0.f,0.f,0.f,0.f,0.f,0.f,0.f};   // hoisted C-bank
    const float vmask = __uint_as_float(0xFFFFFC00u);

    float kmin0 = 1e30f, kmin1 = 1e30f;
    const int sp0 = blockIdx.y * SPG;

    // ---- prologue: load + convert split sp0 into buffer 0
    float2 r0a, r0b, r1a, r1b;
    {
        const int j0 = sp0 * 512 + threadIdx.x;
        const float2* p0 = (const float2*)(gt + j0 * 6);
        const float2* p1 = (const float2*)(gt + (j0 + 256) * 6);
        r0a = p0[0]; r0b = p0[1];
        r1a = p1[0]; r1b = p1[1];
    }
    conv_row(r0a.x, r0a.y, r0b.x, AF[0], threadIdx.x);
    conv_row(r1a.x, r1a.y, r1b.x, AF[0], threadIdx.x + 256);
    __syncthreads();

#pragma unroll 1
    for (int u = 0; u < SPG; ++u) {
        const int sp = sp0 + u;
        uint4* cur = AF[u & 1];
        uint4* nxt = AF[(u + 1) & 1];
        const bool more = (u + 1 < SPG);

        if (more) {  // issue next split's global loads (latency hides under compute)
            const int j0 = (sp + 1) * 512 + threadIdx.x;
            const float2* p0 = (const float2*)(gt + j0 * 6);
            const float2* p1 = (const float2*)(gt + (j0 + 256) * 6);
            r0a = p0[0]; r0b = p0[1];
            r1a = p1[0]; r1b = p1[1];
        }

        __builtin_amdgcn_s_setprio(1);                  // T5: favor compute waves
        const int t0 = sp * TPS;
#pragma unroll 2
        for (int tt = 0; tt < TPS; tt += 2) {
            const uint4 aua = cur[tt * 64 + l];
            const uint4 aub = cur[(tt + 1) * 64 + l];
            const short8 ava = *(const short8*)&aua;
            const short8 avb = *(const short8*)&aub;
            const int ga = t0 + tt, gb = t0 + tt + 1;   // wave-uniform (SGPR)

            f32x16 acc_a0, acc_b0, acc_a1, acc_b1;
            MFMA_V(acc_a0, ava, bv0, zacc);
            MFMA_V(acc_b0, avb, bv0, zacc);
            MFMA_V(acc_a1, ava, bv1, zacc);
            MFMA_V(acc_b1, avb, bv1, zacc);

            const float ka0 = tile_key3(acc_a0, vmask, ga);
            const float kb0 = tile_key3(acc_b0, vmask, gb);
            asm("v_min3_f32 %0, %0, %1, %2" : "+v"(kmin0) : "v"(ka0), "v"(kb0));
            const float ka1 = tile_key3(acc_a1, vmask, ga);
            const float kb1 = tile_key3(acc_b1, vmask, gb);
            asm("v_min3_f32 %0, %0, %1, %2" : "+v"(kmin1) : "v"(ka1), "v"(kb1));
        }
        __builtin_amdgcn_s_setprio(0);

        if (more) {  // convert + LDS-write after compute (T14 write-late)
            conv_row(r0a.x, r0a.y, r0b.x, nxt, threadIdx.x);
            conv_row(r1a.x, r1a.y, r1b.x, nxt, threadIdx.x + 256);
        }
        __syncthreads();
    }

    // cross-half merges (lane l <-> l+32 hold complementary rows)
    kmin0 = fminf(kmin0, __shfl_xor(kmin0, 32, 64));
    kmin1 = fminf(kmin1, __shfl_xor(kmin1, 32, 64));

    const float km = hi ? kmin1 : kmin0;
    packed2[(size_t)(pbase + l) * NGROUP + blockIdx.y] = __float_as_uint(km);
}

// ---------------------------------------------------------------------------
// rescan: 2048 blocks x 8 preds. Per pred: lanes 0-15 load the pred's 16
// group keys (64 B contiguous), fminf shuffle-reduce, tile = bits & 0x3FF;
// exact fp32 argmin in the winning 32-row tile (first occurrence; float2
// position loads); normals cosine; per-block partial. No atomics, no fences.
// ---------------------------------------------------------------------------
__global__ __launch_bounds__(256) void rescan_kernel(
    const float* __restrict__ pred,
    const float* __restrict__ gt,
    const unsigned* __restrict__ packed2,
    float* __restrict__ partials)
{
    __shared__ float part[8];
    const int w = threadIdx.x >> 6, l = threadIdx.x & 63;
    const int half = l >> 5, jl = l & 31;
    const int pi = blockIdx.x * 8 + w * 2 + half;

    const unsigned* kp = packed2 + (size_t)pi * NGROUP;
    float e = (jl < NGROUP) ? __uint_as_float(kp[jl]) : 1e30f;
#pragma unroll
    for (int off = 16; off; off >>= 1)
        e = fminf(e, __shfl_xor(e, off, 32));
    const unsigned tix = __float_as_uint(e) & 0x3FFu;   // winning 32-row tile

    const int row = (int)tix * 32 + jl;
    const float2* gr = (const float2*)(gt + row * 6);   // 24 B rows, 8 B aligned
    const float2 ga = gr[0], gb = gr[1];
    const float gx = ga.x, gy = ga.y, gz = gb.x;
    const float g2 = fmaf(gx, gx, fmaf(gy, gy, gz * gz));
    const float2* pr = (const float2*)(pred + pi * 6);
    const float2 pa = pr[0], pb = pr[1];
    const float px = pa.x, py = pa.y, pz = pb.x;
    float d = fmaf(px, -2.0f * gx, fmaf(py, -2.0f * gy, fmaf(pz, -2.0f * gz, g2)));
    int jj = jl;
#pragma unroll
    for (int off = 16; off; off >>= 1) {
        const float d2 = __shfl_xor(d, off, 32);
        const int   j2 = __shfl_xor(jj, off, 32);
        const bool t = (d2 < d) || (d2 == d && j2 < jj);
        d  = t ? d2 : d;
        jj = t ? j2 : jj;
    }
    if (jl == 0) {
        const int idx = (int)tix * 32 + jj;
        const float nx = pred[pi * 6 + 3], ny = pred[pi * 6 + 4], nz = pred[pi * 6 + 5];
        const float ax = gt[idx * 6 + 3],  ay = gt[idx * 6 + 4],  az = gt[idx * 6 + 5];
        const float pn = fmaxf(sqrtf(fmaf(nx, nx, fmaf(ny, ny, nz * nz))), 1e-12f);
        const float gn = fmaxf(sqrtf(fmaf(ax, ax, fmaf(ay, ay, az * az))), 1e-12f);
        part[w * 2 + half] = 1.0f - fmaf(nx, ax, fmaf(ny, ay, nz * az)) / (pn * gn);
    }
    __syncthreads();
    if (threadIdx.x == 0) {
        float s = 0.f;
#pragma unroll
        for (int i = 0; i < 8; ++i) s += part[i];
        partials[blockIdx.x] = s;
    }
}

// ---------------------------------------------------------------------------
// final: sum partials + regularizer, single write to out[0].
// ---------------------------------------------------------------------------
__global__ __launch_bounds__(256) void final_kernel(
    const float* __restrict__ partials,
    const float* __restrict__ Rm,
    const float* __restrict__ tv,
    const float* __restrict__ sv,
    float* __restrict__ out)
{
    __shared__ float ws_[4];
    float s = 0.f;
    for (int i = threadIdx.x; i < RESB; i += 256) s += partials[i];
#pragma unroll
    for (int off = 32; off; off >>= 1) s += __shfl_down(s, off, 64);
    if ((threadIdx.x & 63) == 0) ws_[threadIdx.x >> 6] = s;
    __syncthreads();
    if (threadIdx.x == 0) {
        const float t = ws_[0] + ws_[1] + ws_[2] + ws_[3];
        float rs = 0.f;
#pragma unroll
        for (int k = 0; k < 9; ++k) {
            const float v = Rm[k] - ((k % 4 == 0) ? 1.0f : 0.0f);
            rs = fmaf(v, v, rs);
        }
        const float rot = sqrtf(rs);
        const float tr  = sqrtf(fmaf(tv[0], tv[0], fmaf(tv[1], tv[1], tv[2] * tv[2])));
        const float sc  = (sv[0] - 1.0f) * (sv[0] - 1.0f);
        out[0] = GAMMA * t / (float)NPRED + BETA * (rot + tr + sc);
    }
}

extern "C" void kernel_launch(void* const* d_in, const int* in_sizes, int n_in,
                              void* d_out, int out_size, void* d_ws, size_t ws_size,
                              hipStream_t stream)
{
    const float* pred = (const float*)d_in[0];
    const float* gt   = (const float*)d_in[1];
    const float* Rm   = (const float*)d_in[2];
    const float* tv   = (const float*)d_in[3];
    const float* sv   = (const float*)d_in[4];
    float* out = (float*)d_out;

    unsigned* packed2 = (unsigned*)d_ws;                                  // 1 MB
    float* partials   = (float*)((char*)d_ws + (size_t)NPRED * NGROUP * 4);   // 8 KB

    nn_kernel<<<dim3(NN_BX, NGROUP), 256, 0, stream>>>(pred, gt, packed2);
    rescan_kernel<<<RESB, 256, 0, stream>>>(pred, gt, packed2, partials);
    final_kernel<<<1, 256, 0, stream>>>(partials, Rm, tv, sv, out);
}